// Round 4
// baseline (1230.083 us; speedup 1.0000x reference)
//
#include <hip/hip_runtime.h>
#include <math.h>

#define NT 16384
#define DIM 4096
#define NE 64
#define TOPK 8
#define TM 16        /* tokens per block */
#define NW 4         /* waves per block = K-slices */
#define CPS 256      /* float4 chunks per K-slice (1024 dims) */
#define DELTA 2e-4f  /* near-tie flag threshold on fp32 logit gaps */

// d_out layout (floats), concatenated flat in reference return order:
#define OFF_IDS 0
#define OFF_PROBS (NT * TOPK)
#define OFF_SIDS (2 * NT * TOPK)
#define OFF_SPROBS (OFF_SIDS + NT * 2)
#define OFF_AUX (OFF_SPROBS + NT * 2)

// d_ws layout (float indices):
#define WS_WP 0            /* 262144 floats: W packed [chunk][expert][4] */
#define WS_RED1 262144     /* 1024*64 floats: per-block prob sums */
#define WS_CNT 327680      /* 1 int: flagged count */
#define WS_LIST 327681     /* up to 16384 ints: flagged tokens */

// Pack W[64][4096] -> Wp[c][e][4] so lane e reads a contiguous float4 per chunk.
__global__ void pack_w_kernel(const float* __restrict__ W, float* __restrict__ Wp) {
    int idx = blockIdx.x * blockDim.x + threadIdx.x;  // 0..262143
    int j = idx & 3;
    int e = (idx >> 2) & 63;
    int c = idx >> 8;
    Wp[idx] = W[e * DIM + c * 4 + j];
}

__global__ void zero_cnt_kernel(int* __restrict__ cnt) {
    if (threadIdx.x == 0) *cnt = 0;
}

// Block: 16 tokens x 64 experts, 4 waves each computing a 1024-dim K-slice in
// fp32, LDS-combined; fused softmax + top-9 gap check + outputs + aux partial.
__launch_bounds__(256, 4)
__global__ void router_main_kernel(const float* __restrict__ x,
                                   const float* __restrict__ Wp,
                                   const float* __restrict__ bias,
                                   float* __restrict__ out,
                                   float* __restrict__ red1,
                                   int* __restrict__ cnt,
                                   int* __restrict__ list) {
    __shared__ float sh[NW * TM * NE];  // 16 KB: [slice][token][expert]
    __shared__ float sh2[NW * NE];      // 1 KB: per-wave aux partials
    const int lane = threadIdx.x & 63;
    const int wave = threadIdx.x >> 6;
    const int blk = blockIdx.x;
    const int tokBase = __builtin_amdgcn_readfirstlane(blk * TM);

    const float4* __restrict__ x4 = (const float4*)x;
    const float4* __restrict__ w4 = (const float4*)Wp;

    float acc[TM];
#pragma unroll
    for (int t = 0; t < TM; ++t) acc[t] = 0.f;

    const int cbase = wave * CPS;
#pragma unroll 2
    for (int db = 0; db < CPS; ++db) {
        const int c = cbase + db;
        float4 wv = w4[c * 64 + lane];  // coalesced 1KB/wave, L2-resident
#pragma unroll
        for (int t = 0; t < TM; ++t) {
            float4 xv = x4[(tokBase + t) * (DIM / 4) + c];  // uniform -> s_load
            acc[t] = fmaf(xv.x, wv.x, acc[t]);
            acc[t] = fmaf(xv.y, wv.y, acc[t]);
            acc[t] = fmaf(xv.z, wv.z, acc[t]);
            acc[t] = fmaf(xv.w, wv.w, acc[t]);
        }
    }
#pragma unroll
    for (int t = 0; t < TM; ++t) sh[wave * (TM * NE) + t * NE + lane] = acc[t];
    __syncthreads();

    const float b = bias[lane];
    float pacc = 0.f;  // per-lane (= per-expert) prob sum over this wave's tokens

#pragma unroll
    for (int tt = 0; tt < TM / NW; ++tt) {
        const int t = wave * (TM / NW) + tt;
        const int tok = tokBase + t;
        const float lv = sh[0 * (TM * NE) + t * NE + lane] +
                         sh[1 * (TM * NE) + t * NE + lane] +
                         sh[2 * (TM * NE) + t * NE + lane] +
                         sh[3 * (TM * NE) + t * NE + lane] + b;

        // softmax over 64 lanes (fp32: probs threshold is 2% relative)
        float m = lv;
#pragma unroll
        for (int off = 32; off; off >>= 1) m = fmaxf(m, __shfl_xor(m, off, 64));
        const float ev = __expf(lv - m);
        float s = ev;
#pragma unroll
        for (int off = 32; off; off >>= 1) s += __shfl_xor(s, off, 64);
        const float prob = ev / s;
        pacc += prob;

        // top-9 selection: top-8 outputs + 9th value for the boundary gap.
        float cur = lv;
        float prevv = 0.f, mingap = 1e30f;
        float myid = 0.f, mypv = 0.f;
        for (int k = 0; k < TOPK + 1; ++k) {
            float bv = cur;
            int bi = lane;
#pragma unroll
            for (int off = 32; off; off >>= 1) {
                float ov = __shfl_xor(bv, off, 64);
                int oi = __shfl_xor(bi, off, 64);
                if (ov > bv || (ov == bv && oi < bi)) { bv = ov; bi = oi; }
            }
            if (k > 0) mingap = fminf(mingap, prevv - bv);
            prevv = bv;
            if (k < TOPK) {
                const float bp = __shfl(prob, bi, 64);
                if (lane == k) { myid = (float)bi; mypv = bp; }
                if (lane == bi) cur = -INFINITY;
            }
        }
        if (lane < TOPK) {
            out[OFF_IDS + tok * TOPK + lane] = myid;
            out[OFF_PROBS + tok * TOPK + lane] = mypv;
        }
        if (lane < 2) {
            out[OFF_SIDS + tok * 2 + lane] = (float)lane;
            out[OFF_SPROBS + tok * 2 + lane] = 0.5f;
        }
        // near-tie among top-9 -> fp64 cleanup pass will redo this token
        if (lane == 0 && mingap < DELTA) {
            int p = atomicAdd(cnt, 1);
            list[p] = tok;
        }
    }

    sh2[wave * NE + lane] = pacc;
    __syncthreads();
    if (wave == 0) {
        red1[blk * NE + lane] =
            sh2[lane] + sh2[64 + lane] + sh2[128 + lane] + sh2[192 + lane];
    }
}

// Exact fp64 recompute of flagged (near-tie) tokens; overwrites ids+probs.
__launch_bounds__(256, 1)
__global__ void cleanup_kernel(const float* __restrict__ x,
                               const float* __restrict__ W,
                               const float* __restrict__ bias,
                               float* __restrict__ out,
                               const int* __restrict__ cnt,
                               const int* __restrict__ list) {
    const int lane = threadIdx.x & 63;
    const int waveG = (blockIdx.x * blockDim.x + threadIdx.x) >> 6;  // 0..1023
    const int n = *cnt;
    for (int i = waveG; i < n; i += 1024) {
        const int tok = list[i];
        const float4* wr = (const float4*)(W + lane * DIM);
        const float4* xr = (const float4*)(x + (size_t)tok * DIM);
        double a0 = 0, a1 = 0, a2 = 0, a3 = 0;
        for (int c = 0; c < DIM / 4; ++c) {
            float4 wv = wr[c];
            float4 xv = xr[c];
            a0 = fma((double)xv.x, (double)wv.x, a0);
            a1 = fma((double)xv.y, (double)wv.y, a1);
            a2 = fma((double)xv.z, (double)wv.z, a2);
            a3 = fma((double)xv.w, (double)wv.w, a3);
        }
        const double lv = ((a0 + a1) + (a2 + a3)) + (double)bias[lane];

        double m = lv;
#pragma unroll
        for (int off = 32; off; off >>= 1) m = fmax(m, __shfl_xor(m, off, 64));
        const double ev = exp(lv - m);
        double s = ev;
#pragma unroll
        for (int off = 32; off; off >>= 1) s += __shfl_xor(s, off, 64);
        const double prob = ev / s;

        double cur = lv;
        float myid = 0.f, mypv = 0.f;
        for (int k = 0; k < TOPK; ++k) {
            double bv = cur;
            int bi = lane;
#pragma unroll
            for (int off = 32; off; off >>= 1) {
                double ov = __shfl_xor(bv, off, 64);
                int oi = __shfl_xor(bi, off, 64);
                if (ov > bv || (ov == bv && oi < bi)) { bv = ov; bi = oi; }
            }
            const double bp = __shfl(prob, bi, 64);
            if (lane == k) { myid = (float)bi; mypv = (float)bp; }
            if (lane == bi) cur = -INFINITY;
        }
        if (lane < TOPK) {
            out[OFF_IDS + tok * TOPK + lane] = myid;
            out[OFF_PROBS + tok * TOPK + lane] = mypv;
        }
    }
}

__global__ void reduce_aux_kernel(const float* __restrict__ red1,
                                  float* __restrict__ out) {
    __shared__ float sm[256];
    const int t = threadIdx.x;
    const int e = t & 63;
    const int g = t >> 6;
    float s = 0.f;
    for (int i = g; i < 1024; i += 4) s += red1[i * 64 + e];
    sm[t] = s;
    __syncthreads();
    if (t < 64) {
        float tot = sm[t] + sm[t + 64] + sm[t + 128] + sm[t + 192];
        float mean = tot * (1.0f / (float)NT);
        float sq = mean * mean;
#pragma unroll
        for (int off = 32; off; off >>= 1) sq += __shfl_xor(sq, off, 64);
        if (t == 0) out[OFF_AUX] = 0.01f * (sq * (1.0f / (float)NE));
    }
}

extern "C" void kernel_launch(void* const* d_in, const int* in_sizes, int n_in,
                              void* d_out, int out_size, void* d_ws, size_t ws_size,
                              hipStream_t stream) {
    const float* x = (const float*)d_in[0];
    const float* W = (const float*)d_in[1];
    const float* bias = (const float*)d_in[2];
    float* out = (float*)d_out;

    float* Wp = (float*)d_ws + WS_WP;
    float* red1 = (float*)d_ws + WS_RED1;
    int* cnt = (int*)((float*)d_ws + WS_CNT);
    int* list = (int*)((float*)d_ws + WS_LIST);

    pack_w_kernel<<<1024, 256, 0, stream>>>(W, Wp);
    zero_cnt_kernel<<<1, 64, 0, stream>>>(cnt);
    router_main_kernel<<<1024, 256, 0, stream>>>(x, Wp, bias, out, red1, cnt, list);
    cleanup_kernel<<<256, 256, 0, stream>>>(x, W, bias, out, cnt, list);
    reduce_aux_kernel<<<1, 256, 0, stream>>>(red1, out);
}

// Round 5
// 645.149 us; speedup vs baseline: 1.9067x; 1.9067x over previous
//
#include <hip/hip_runtime.h>
#include <math.h>

#define NT 16384
#define DIM 4096
#define NE 64
#define TOPK 8
#define NSTEP 128          /* K-steps of 32 */
#define DELTA 2e-4f        /* near-tie flag threshold on fp32 logit gaps */

typedef __attribute__((ext_vector_type(8))) short short8;
typedef __attribute__((ext_vector_type(4))) float f32x4;

// d_out layout (floats), concatenated flat in reference return order:
#define OFF_IDS 0
#define OFF_PROBS (NT * TOPK)
#define OFF_SIDS (2 * NT * TOPK)
#define OFF_SPROBS (OFF_SIDS + NT * 2)
#define OFF_AUX (OFF_SPROBS + NT * 2)

// d_ws layout (float indices):
#define WS_AUX 262144      /* 64 floats: per-expert prob sums */
#define WS_CNT 262208      /* 1 int: flagged count */
#define WS_LIST 262209     /* up to 16384 ints: flagged tokens */

__device__ inline unsigned short f2bf(float f) {
    unsigned u = __builtin_bit_cast(unsigned, f);
    u = (u + 0x7FFFu + ((u >> 16) & 1u)) >> 16;   // round-to-nearest-even
    return (unsigned short)u;
}
__device__ inline float bf2f(unsigned short h) {
    unsigned u = ((unsigned)h) << 16;
    return __builtin_bit_cast(float, u);
}

// Pack W[64][4096] fp32 -> Wpk[step][tile][split][lane] of short8 (16B), the
// exact B-fragment each lane feeds mfma_f32_16x16x32_bf16:
//   lane l of tile t holds B[k = step*32 + (l>>4)*8 + j][n = t*16 + (l&15)].
// split 0 = bf16(hi), split 1 = bf16(w - hi).
__global__ void pack_w_kernel(const float* __restrict__ W, short8* __restrict__ Wpk) {
    int tau = blockIdx.x * blockDim.x + threadIdx.x;  // 0..65535
    int lane = tau & 63;
    int sp = (tau >> 6) & 1;
    int tile = (tau >> 7) & 3;
    int step = tau >> 9;
    int e = tile * 16 + (lane & 15);
    int kb = step * 32 + (lane >> 4) * 8;
    const float* wr = W + e * DIM + kb;
    short8 o;
#pragma unroll
    for (int j = 0; j < 8; ++j) {
        float v = wr[j];
        unsigned short hb = f2bf(v);
        o[j] = (sp == 0) ? (short)hb : (short)f2bf(v - bf2f(hb));
    }
    Wpk[tau] = o;
}

__global__ void zero_kernel(float* __restrict__ aux, int* __restrict__ cnt) {
    int t = threadIdx.x;
    if (t < 64) aux[t] = 0.f;
    if (t == 64) *cnt = 0;
}

#define LOAD_B(BUF, S) { \
    const short8* _p = wp + (size_t)(S) * 512 + lane; \
    _Pragma("unroll") \
    for (int _f = 0; _f < 8; ++_f) Bbuf[BUF][_f] = _p[_f * 64]; }

#define LOAD_X(PH, S) { \
    _Pragma("unroll") \
    for (int _mt = 0; _mt < 2; ++_mt) { \
        const float4* _p = xrow[_mt] + (size_t)(S) * 8; \
        Xb[PH][_mt][0] = _p[0]; \
        Xb[PH][_mt][1] = _p[1]; } }

#define CVT4(DH, DM, BASE, V) { \
    float _q0 = (V).x, _q1 = (V).y, _q2 = (V).z, _q3 = (V).w; \
    unsigned short _h0 = f2bf(_q0), _h1 = f2bf(_q1), _h2 = f2bf(_q2), _h3 = f2bf(_q3); \
    DH[(BASE)+0] = (short)_h0; DH[(BASE)+1] = (short)_h1; \
    DH[(BASE)+2] = (short)_h2; DH[(BASE)+3] = (short)_h3; \
    DM[(BASE)+0] = (short)f2bf(_q0 - bf2f(_h0)); DM[(BASE)+1] = (short)f2bf(_q1 - bf2f(_h1)); \
    DM[(BASE)+2] = (short)f2bf(_q2 - bf2f(_h2)); DM[(BASE)+3] = (short)f2bf(_q3 - bf2f(_h3)); }

#define COMPUTE(PH, BB) { \
    _Pragma("unroll") \
    for (int _mt = 0; _mt < 2; ++_mt) { \
        short8 _ahi, _amid; \
        CVT4(_ahi, _amid, 0, Xb[PH][_mt][0]); \
        CVT4(_ahi, _amid, 4, Xb[PH][_mt][1]); \
        _Pragma("unroll") \
        for (int _t = 0; _t < 4; ++_t) { \
            acc[_mt][_t] = __builtin_amdgcn_mfma_f32_16x16x32_bf16(_ahi,  Bbuf[BB][_t*2+0], acc[_mt][_t], 0, 0, 0); \
            acc[_mt][_t] = __builtin_amdgcn_mfma_f32_16x16x32_bf16(_amid, Bbuf[BB][_t*2+0], acc[_mt][_t], 0, 0, 0); \
            acc[_mt][_t] = __builtin_amdgcn_mfma_f32_16x16x32_bf16(_ahi,  Bbuf[BB][_t*2+1], acc[_mt][_t], 0, 0, 0); } } }

// Block = 128 thr = 2 waves; wave handles 32 tokens x 64 experts.
// A-frag: lane l holds x[tok = base + (l&15) (+16 for mt=1)][k = s*32 + (l>>4)*8 + j].
__launch_bounds__(128, 1)
__global__ void router_mfma_kernel(const float* __restrict__ x,
                                   const short8* __restrict__ wp,
                                   const float* __restrict__ bias,
                                   float* __restrict__ out,
                                   float* __restrict__ aux,
                                   int* __restrict__ cnt,
                                   int* __restrict__ list) {
    const int lane = threadIdx.x & 63;
    const int wv = threadIdx.x >> 6;                 // 0..1
    const int tokBase = blockIdx.x * 64 + wv * 32;
    const int g = lane >> 4;                         // 16-lane group 0..3
    const int c = lane & 15;                         // col within tile

    const float4* x4 = (const float4*)x;
    const float4* xrow[2];
    xrow[0] = x4 + (size_t)(tokBase + c) * (DIM / 4) + g * 2;
    xrow[1] = xrow[0] + 16 * (DIM / 4);

    f32x4 acc[2][4];
#pragma unroll
    for (int mt = 0; mt < 2; ++mt)
#pragma unroll
        for (int t = 0; t < 4; ++t) acc[mt][t] = (f32x4){0.f, 0.f, 0.f, 0.f};

    short8 Bbuf[2][8];
    float4 Xb[4][2][2];

    // prologue: B(step0)->buf0, X(step0)->ph0, X(step1)->ph1
    LOAD_B(0, 0)
    LOAD_X(0, 0)
    LOAD_X(1, 1)

    for (int s = 0; s < NSTEP; s += 4) {
        { int sb = s + 1;                            LOAD_B(1, sb)
          int sx = s + 2; if (sx >= NSTEP) sx = 0;   LOAD_X(2, sx) }
        COMPUTE(0, 0)
        { int sb = s + 2; if (sb >= NSTEP) sb = 0;   LOAD_B(0, sb)
          int sx = s + 3; if (sx >= NSTEP) sx = 0;   LOAD_X(3, sx) }
        COMPUTE(1, 1)
        { int sb = s + 3; if (sb >= NSTEP) sb = 0;   LOAD_B(1, sb)
          int sx = s + 4; if (sx >= NSTEP) sx = 0;   LOAD_X(0, sx) }
        COMPUTE(2, 0)
        { int sb = s + 4; if (sb >= NSTEP) sb = 0;   LOAD_B(0, sb)
          int sx = s + 5; if (sx >= NSTEP) sx = 0;   LOAD_X(1, sx) }
        COMPUTE(3, 1)
    }

    // ---- epilogue: per token (C layout: token=(l>>4)*4+reg, expert=t*16+(l&15)) ----
    float bt[4];
#pragma unroll
    for (int t = 0; t < 4; ++t) bt[t] = bias[t * 16 + c];

    float paux[4] = {0.f, 0.f, 0.f, 0.f};

#pragma unroll
    for (int mt = 0; mt < 2; ++mt) {
#pragma unroll
        for (int r = 0; r < 4; ++r) {
            const int tok = tokBase + mt * 16 + g * 4 + r;
            float lv[4];
#pragma unroll
            for (int t = 0; t < 4; ++t) lv[t] = acc[mt][t][r] + bt[t];

            // softmax across this token's 64 experts (16 lanes x 4 tiles)
            float m = fmaxf(fmaxf(lv[0], lv[1]), fmaxf(lv[2], lv[3]));
#pragma unroll
            for (int off = 8; off; off >>= 1) m = fmaxf(m, __shfl_xor(m, off, 64));
            float p[4];
            float ssum = 0.f;
#pragma unroll
            for (int t = 0; t < 4; ++t) { p[t] = __expf(lv[t] - m); ssum += p[t]; }
#pragma unroll
            for (int off = 8; off; off >>= 1) ssum += __shfl_xor(ssum, off, 64);
            const float inv = 1.0f / ssum;
#pragma unroll
            for (int t = 0; t < 4; ++t) { p[t] *= inv; paux[t] += p[t]; }

            // top-9 by logit (monotone with prob); tie-break lower expert id
            float cur[4] = {lv[0], lv[1], lv[2], lv[3]};
            float prevv = 0.f, mingap = 1e30f;
            for (int k = 0; k < TOPK + 1; ++k) {
                float bv = cur[0];
                int bid = c;
#pragma unroll
                for (int t = 1; t < 4; ++t) {
                    int id = t * 16 + c;
                    if (cur[t] > bv || (cur[t] == bv && id < bid)) { bv = cur[t]; bid = id; }
                }
#pragma unroll
                for (int off = 8; off; off >>= 1) {
                    float ov = __shfl_xor(bv, off, 64);
                    int oid = __shfl_xor(bid, off, 64);
                    if (ov > bv || (ov == bv && oid < bid)) { bv = ov; bid = oid; }
                }
                if (k > 0) mingap = fminf(mingap, prevv - bv);
                prevv = bv;
                if (k < TOPK) {
                    const int wt = bid >> 4, wc = bid & 15;
                    float pw = (wt == 0) ? p[0] : (wt == 1) ? p[1] : (wt == 2) ? p[2] : p[3];
                    pw = __shfl(pw, (lane & 48) | wc, 64);
                    if (c == k) {
                        out[OFF_IDS + tok * TOPK + k] = (float)bid;
                        out[OFF_PROBS + tok * TOPK + k] = pw;
                    }
#pragma unroll
                    for (int t = 0; t < 4; ++t)
                        cur[t] = (t == wt && c == wc) ? -INFINITY : cur[t];
                }
            }
            if (c < 2) {
                out[OFF_SIDS + tok * 2 + c] = (float)c;
                out[OFF_SPROBS + tok * 2 + c] = 0.5f;
            }
            if (c == 0 && mingap < DELTA) {
                int pos = atomicAdd(cnt, 1);
                list[pos] = tok;
            }
        }
    }

    // aux partials: expert e = t*16+c
    __shared__ float shaux[64];
    if (threadIdx.x < 64) shaux[threadIdx.x] = 0.f;
    __syncthreads();
#pragma unroll
    for (int t = 0; t < 4; ++t) atomicAdd(&shaux[t * 16 + c], paux[t]);
    __syncthreads();
    if (threadIdx.x < 64) atomicAdd(aux + threadIdx.x, shaux[threadIdx.x]);
}

// Exact fp64 recompute of flagged (near-tie) tokens; overwrites ids+probs.
__launch_bounds__(256, 1)
__global__ void cleanup_kernel(const float* __restrict__ x,
                               const float* __restrict__ W,
                               const float* __restrict__ bias,
                               float* __restrict__ out,
                               const int* __restrict__ cnt,
                               const int* __restrict__ list) {
    const int lane = threadIdx.x & 63;
    const int waveG = (blockIdx.x * blockDim.x + threadIdx.x) >> 6;  // 0..1023
    const int n = *cnt;
    for (int i = waveG; i < n; i += 1024) {
        const int tok = list[i];
        const float4* wr = (const float4*)(W + lane * DIM);
        const float4* xr = (const float4*)(x + (size_t)tok * DIM);
        double a0 = 0, a1 = 0, a2 = 0, a3 = 0;
        for (int cc = 0; cc < DIM / 4; ++cc) {
            float4 wv = wr[cc];
            float4 xv = xr[cc];
            a0 = fma((double)xv.x, (double)wv.x, a0);
            a1 = fma((double)xv.y, (double)wv.y, a1);
            a2 = fma((double)xv.z, (double)wv.z, a2);
            a3 = fma((double)xv.w, (double)wv.w, a3);
        }
        const double lv = ((a0 + a1) + (a2 + a3)) + (double)bias[lane];

        double m = lv;
#pragma unroll
        for (int off = 32; off; off >>= 1) m = fmax(m, __shfl_xor(m, off, 64));
        const double ev = exp(lv - m);
        double s = ev;
#pragma unroll
        for (int off = 32; off; off >>= 1) s += __shfl_xor(s, off, 64);
        const double prob = ev / s;

        double cur = lv;
        float myid = 0.f, mypv = 0.f;
        for (int k = 0; k < TOPK; ++k) {
            double bv = cur;
            int bi = lane;
#pragma unroll
            for (int off = 32; off; off >>= 1) {
                double ov = __shfl_xor(bv, off, 64);
                int oi = __shfl_xor(bi, off, 64);
                if (ov > bv || (ov == bv && oi < bi)) { bv = ov; bi = oi; }
            }
            const double bp = __shfl(prob, bi, 64);
            if (lane == k) { myid = (float)bi; mypv = (float)bp; }
            if (lane == bi) cur = -INFINITY;
        }
        if (lane < TOPK) {
            out[OFF_IDS + tok * TOPK + lane] = myid;
            out[OFF_PROBS + tok * TOPK + lane] = mypv;
        }
    }
}

__global__ void aux_final_kernel(const float* __restrict__ aux, float* __restrict__ out) {
    const int l = threadIdx.x;  // 64
    float v = aux[l] * (1.0f / (float)NT);
    float sq = v * v;
#pragma unroll
    for (int off = 32; off; off >>= 1) sq += __shfl_xor(sq, off, 64);
    if (l == 0) out[OFF_AUX] = 0.01f * (sq * (1.0f / (float)NE));
}

extern "C" void kernel_launch(void* const* d_in, const int* in_sizes, int n_in,
                              void* d_out, int out_size, void* d_ws, size_t ws_size,
                              hipStream_t stream) {
    const float* x = (const float*)d_in[0];
    const float* W = (const float*)d_in[1];
    const float* bias = (const float*)d_in[2];
    float* out = (float*)d_out;

    short8* Wpk = (short8*)d_ws;                      // 1 MB
    float* aux = (float*)d_ws + WS_AUX;
    int* cnt = (int*)((float*)d_ws + WS_CNT);
    int* list = (int*)((float*)d_ws + WS_LIST);

    pack_w_kernel<<<256, 256, 0, stream>>>(W, Wpk);
    zero_kernel<<<1, 128, 0, stream>>>(aux, cnt);
    router_mfma_kernel<<<256, 128, 0, stream>>>(x, Wpk, bias, out, aux, cnt, list);
    cleanup_kernel<<<256, 256, 0, stream>>>(x, W, bias, out, cnt, list);
    aux_final_kernel<<<1, 64, 0, stream>>>(aux, out);
}